// Round 3
// baseline (99.554 us; speedup 1.0000x reference)
//
#include <hip/hip_runtime.h>
#include <math.h>

typedef float v2f __attribute__((ext_vector_type(2)));

__device__ __forceinline__ v2f v2_min(v2f a, float b) {
    v2f r; r.x = fminf(a.x, b); r.y = fminf(a.y, b); return r;
}
__device__ __forceinline__ v2f v2_max(v2f a, float b) {
    v2f r; r.x = fmaxf(a.x, b); r.y = fmaxf(a.y, b); return r;
}
__device__ __forceinline__ v2f v2_max0(v2f a) {
    v2f r; r.x = fmaxf(a.x, 0.0f); r.y = fmaxf(a.y, 0.0f); return r;
}

// Preprocess gt boxes into workspace, stride 8 floats per gt:
// [x0, y0, x1, y1, area, cls, 0, 0]; invalid gt -> degenerate box (inter==0
// always, area 0) so it can never win the argmax when any positive-IoU gt
// exists, and when it "wins" trivially the output is the index-independent
// -1 fill (q==0 or q==-... <= IOU_LOW path).
__global__ void prep_kernel(const float* __restrict__ gt, float* __restrict__ pre, int m) {
    int j = threadIdx.x;
    if (j < m) {
        float g0 = gt[j * 5 + 0];
        float g1 = gt[j * 5 + 1];
        float g2 = gt[j * 5 + 2];
        float g3 = gt[j * 5 + 3];
        float g4 = gt[j * 5 + 4];
        bool valid = (g4 != -1.0f);
        float* p = pre + j * 8;
        if (valid) {
            p[0] = g0; p[1] = g1; p[2] = g2; p[3] = g3;
            p[4] = (g2 - g0) * (g3 - g1);
        } else {
            p[0] = 1e30f; p[1] = 1e30f; p[2] = -1e30f; p[3] = -1e30f;
            p[4] = 0.0f;
        }
        p[5] = g4; p[6] = 0.0f; p[7] = 0.0f;
    }
}

__global__ __launch_bounds__(256) void rpn_match_kernel(
    const float* __restrict__ anchors,
    const float* __restrict__ deltas,
    const float* __restrict__ pre,     // preprocessed gt, 8 floats/gt, wave-uniform reads
    float* __restrict__ out,
    int n, int m)
{
    const int tid = threadIdx.x;
    // two anchors per thread: i0 and i0+256 (both coalesced)
    const int i0 = blockIdx.x * 512 + tid;
    const int i1 = i0 + 256;
    const bool v0 = (i0 < n);
    const bool v1 = (i1 < n);
    const int i0c = v0 ? i0 : 0;
    const int i1c = v1 ? i1 : 0;

    const float4 a0 = reinterpret_cast<const float4*>(anchors)[i0c];
    const float4 a1 = reinterpret_cast<const float4*>(anchors)[i1c];
    const float4 d0 = reinterpret_cast<const float4*>(deltas)[i0c];
    const float4 d1 = reinterpret_cast<const float4*>(deltas)[i1c];

    // ---- proposals (ulp-tolerant path) ----
    const float SCALE_CLAMP = 3.3322045101752038f; // log(224/8)
    {
        float pw = (a0.z - a0.x) * 0.5f, ph = (a0.w - a0.y) * 0.5f;
        float px = (a0.x + a0.z) * 0.5f, py = (a0.y + a0.w) * 0.5f;
        float bx = px + pw * d0.x, by = py + ph * d0.y;
        float bw = pw * expf(fminf(d0.z, SCALE_CLAMP));
        float bh = ph * expf(fminf(d0.w, SCALE_CLAMP));
        if (v0) reinterpret_cast<float4*>(out)[i0] =
            make_float4(bx - bw, by - bh, bx + bw, by + bh);
    }
    {
        float pw = (a1.z - a1.x) * 0.5f, ph = (a1.w - a1.y) * 0.5f;
        float px = (a1.x + a1.z) * 0.5f, py = (a1.y + a1.w) * 0.5f;
        float bx = px + pw * d1.x, by = py + ph * d1.y;
        float bw = pw * expf(fminf(d1.z, SCALE_CLAMP));
        float bh = ph * expf(fminf(d1.w, SCALE_CLAMP));
        if (v1) reinterpret_cast<float4*>(out)[i1] =
            make_float4(bx - bw, by - bh, bx + bw, by + bh);
    }

    // ---- divide-free IoU argmax, packed across the 2 anchors ----
    // iou_j > iou_b  <=>  inter_j*S_b > inter_b*S_j   (S = area1+area2 > 0)
    v2f ax; ax.x = a0.x; ax.y = a1.x;
    v2f ay; ay.x = a0.y; ay.y = a1.y;
    v2f az; az.x = a0.z; az.y = a1.z;
    v2f aw; aw.x = a0.w; aw.y = a1.w;
    v2f ar; ar.x = (a0.z - a0.x) * (a0.w - a0.y);
            ar.y = (a1.z - a1.x) * (a1.w - a1.y);

    const float4* p4 = reinterpret_cast<const float4*>(pre);

    v2f bI, bS;
    int bidx0 = 0, bidx1 = 0;
    {
        float4 b = p4[0];
        float ga = p4[1].x;
        v2f xl = v2_min(az, b.z) - v2_max(ax, b.x);
        v2f yl = v2_min(aw, b.w) - v2_max(ay, b.y);
        bI = v2_max0(xl) * v2_max0(yl);
        bS = ar + ga;
    }

    #pragma unroll 8
    for (int j = 1; j < m; ++j) {
        float4 b  = p4[2 * j];       // wave-uniform -> s_load
        float  ga = p4[2 * j + 1].x; // wave-uniform -> s_load
        v2f xl = v2_min(az, b.z) - v2_max(ax, b.x);   // pk_add(neg)
        v2f yl = v2_min(aw, b.w) - v2_max(ay, b.y);
        v2f inter = v2_max0(xl) * v2_max0(yl);        // pk_mul
        v2f S = ar + ga;                              // pk_add
        v2f lhs = inter * bS;                         // pk_mul
        v2f rhs = bI * S;                             // pk_mul
        bool g0 = lhs.x > rhs.x;   // strict > = first-occurrence argmax
        bool g1 = lhs.y > rhs.y;
        bI.x  = g0 ? inter.x : bI.x;
        bS.x  = g0 ? S.x     : bS.x;
        bidx0 = g0 ? j       : bidx0;
        bI.y  = g1 ? inter.y : bI.y;
        bS.y  = g1 ? S.y     : bS.y;
        bidx1 = g1 ? j       : bidx1;
    }

    // ---- epilogue: one exact divide per anchor, classify, gather, store ----
    const float IOU_LOW = 0.3f, IOU_HIGH = 0.6f, NEUTRAL = -100000000.0f;
    float* mout = out + (size_t)n * 4;

    {
        float uni = bS.x - bI.x;   // fl(fl(a1+a2) - inter): same assoc as ref
        float q = bI.x / uni;      // bit-identical to ref match_quality
        float o0, o1, o2, o3, o4;
        if (q <= IOU_LOW) {
            o0 = o1 = o2 = o3 = o4 = -1.0f;
        } else if (q < IOU_HIGH) {
            o0 = o1 = o2 = o3 = o4 = NEUTRAL;
        } else {
            float4 gbx = p4[2 * bidx0];
            o0 = gbx.x; o1 = gbx.y; o2 = gbx.z; o3 = gbx.w;
            o4 = p4[2 * bidx0 + 1].y;
        }
        if (v0) {
            float* mo = mout + (size_t)i0 * 5;
            mo[0] = o0; mo[1] = o1; mo[2] = o2; mo[3] = o3; mo[4] = o4;
        }
    }
    {
        float uni = bS.y - bI.y;
        float q = bI.y / uni;
        float o0, o1, o2, o3, o4;
        if (q <= IOU_LOW) {
            o0 = o1 = o2 = o3 = o4 = -1.0f;
        } else if (q < IOU_HIGH) {
            o0 = o1 = o2 = o3 = o4 = NEUTRAL;
        } else {
            float4 gbx = p4[2 * bidx1];
            o0 = gbx.x; o1 = gbx.y; o2 = gbx.z; o3 = gbx.w;
            o4 = p4[2 * bidx1 + 1].y;
        }
        if (v1) {
            float* mo = mout + (size_t)i1 * 5;
            mo[0] = o0; mo[1] = o1; mo[2] = o2; mo[3] = o3; mo[4] = o4;
        }
    }
}

extern "C" void kernel_launch(void* const* d_in, const int* in_sizes, int n_in,
                              void* d_out, int out_size, void* d_ws, size_t ws_size,
                              hipStream_t stream) {
    const float* anchors  = (const float*)d_in[0];
    const float* deltas   = (const float*)d_in[1];
    const float* gt_boxes = (const float*)d_in[2];
    float* out = (float*)d_out;
    float* pre = (float*)d_ws;   // 128 gts * 8 floats = 4 KB scratch

    int n = in_sizes[0] / 4;   // 400000
    int m = in_sizes[2] / 5;   // 128

    hipLaunchKernelGGL(prep_kernel, dim3(1), dim3(256), 0, stream, gt_boxes, pre, m);

    int nblocks = (n + 511) / 512;   // 2 anchors per thread
    hipLaunchKernelGGL(rpn_match_kernel, dim3(nblocks), dim3(256), 0, stream,
                       anchors, deltas, pre, out, n, m);
}

// Round 4
// 98.591 us; speedup vs baseline: 1.0098x; 1.0098x over previous
//
#include <hip/hip_runtime.h>
#include <math.h>

#define MAX_GT 128

typedef float v2f __attribute__((ext_vector_type(2)));

__device__ __forceinline__ v2f v2_min(v2f a, float b) {
    v2f r; r.x = fminf(a.x, b); r.y = fminf(a.y, b); return r;
}
__device__ __forceinline__ v2f v2_max(v2f a, float b) {
    v2f r; r.x = fmaxf(a.x, b); r.y = fmaxf(a.y, b); return r;
}
__device__ __forceinline__ v2f v2_max0(v2f a) {
    v2f r; r.x = fmaxf(a.x, 0.0f); r.y = fmaxf(a.y, 0.0f); return r;
}

__global__ __launch_bounds__(256) void rpn_match_kernel(
    const float* __restrict__ anchors,
    const float* __restrict__ deltas,
    const float* __restrict__ gt_boxes,
    float* __restrict__ out,
    int n, int m)
{
    // One ds_read_b128 per inner iteration: box only. Area computed inline
    // (3 uniform VALU ops << the LDS-pipe cost of a second broadcast read).
    __shared__ float4 sbox[MAX_GT];
    __shared__ float  scls[MAX_GT];

    const int tid = threadIdx.x;
    if (tid < m) {
        float g0 = gt_boxes[tid * 5 + 0];
        float g1 = gt_boxes[tid * 5 + 1];
        float g2 = gt_boxes[tid * 5 + 2];
        float g3 = gt_boxes[tid * 5 + 3];
        float g4 = gt_boxes[tid * 5 + 4];
        bool valid = (g4 != -1.0f);
        // invalid -> (0,0,0,0): inter==0 vs any anchor (x1 = ctr+half > 8),
        // area==0; can never win argmax; trivial win => q=0 <= IOU_LOW path.
        sbox[tid] = valid ? make_float4(g0, g1, g2, g3)
                          : make_float4(0.0f, 0.0f, 0.0f, 0.0f);
        scls[tid] = g4;
    }
    __syncthreads();

    // two anchors per thread: i0 and i0+256 (both coalesced)
    const int i0 = blockIdx.x * 512 + tid;
    const int i1 = i0 + 256;
    const bool v0 = (i0 < n);
    const bool v1 = (i1 < n);
    const int i0c = v0 ? i0 : 0;
    const int i1c = v1 ? i1 : 0;

    const float4 a0 = reinterpret_cast<const float4*>(anchors)[i0c];
    const float4 a1 = reinterpret_cast<const float4*>(anchors)[i1c];
    const float4 d0 = reinterpret_cast<const float4*>(deltas)[i0c];
    const float4 d1 = reinterpret_cast<const float4*>(deltas)[i1c];

    // ---- proposals (ulp-tolerant path) ----
    const float SCALE_CLAMP = 3.3322045101752038f; // log(224/8)
    {
        float pw = (a0.z - a0.x) * 0.5f, ph = (a0.w - a0.y) * 0.5f;
        float px = (a0.x + a0.z) * 0.5f, py = (a0.y + a0.w) * 0.5f;
        float bx = px + pw * d0.x, by = py + ph * d0.y;
        float bw = pw * expf(fminf(d0.z, SCALE_CLAMP));
        float bh = ph * expf(fminf(d0.w, SCALE_CLAMP));
        if (v0) reinterpret_cast<float4*>(out)[i0] =
            make_float4(bx - bw, by - bh, bx + bw, by + bh);
    }
    {
        float pw = (a1.z - a1.x) * 0.5f, ph = (a1.w - a1.y) * 0.5f;
        float px = (a1.x + a1.z) * 0.5f, py = (a1.y + a1.w) * 0.5f;
        float bx = px + pw * d1.x, by = py + ph * d1.y;
        float bw = pw * expf(fminf(d1.z, SCALE_CLAMP));
        float bh = ph * expf(fminf(d1.w, SCALE_CLAMP));
        if (v1) reinterpret_cast<float4*>(out)[i1] =
            make_float4(bx - bw, by - bh, bx + bw, by + bh);
    }

    // ---- divide-free IoU argmax, packed across the 2 anchors ----
    // iou_j > iou_b  <=>  inter_j*S_b > inter_b*S_j   (S = area1+area2 > 0)
    v2f ax; ax.x = a0.x; ax.y = a1.x;
    v2f ay; ay.x = a0.y; ay.y = a1.y;
    v2f az; az.x = a0.z; az.y = a1.z;
    v2f aw; aw.x = a0.w; aw.y = a1.w;
    v2f ar; ar.x = (a0.z - a0.x) * (a0.w - a0.y);
            ar.y = (a1.z - a1.x) * (a1.w - a1.y);

    // init so j==0 always wins the first compare: lhs=I0*1 >= 0 > -S0 = rhs
    v2f bI; bI.x = -1.0f; bI.y = -1.0f;
    v2f bS; bS.x =  1.0f; bS.y =  1.0f;
    int bidx0 = 0, bidx1 = 0;

    #pragma unroll 8
    for (int j = 0; j < m; ++j) {
        float4 b = sbox[j];                      // broadcast ds_read_b128
        float ga = (b.z - b.x) * (b.w - b.y);    // 3 uniform VALU ops
        v2f xl = v2_min(az, b.z) - v2_max(ax, b.x);   // pk_add(neg)
        v2f yl = v2_min(aw, b.w) - v2_max(ay, b.y);
        v2f inter = v2_max0(xl) * v2_max0(yl);        // pk_mul
        v2f S = ar + ga;                              // pk_add
        v2f lhs = inter * bS;                         // pk_mul
        v2f rhs = bI * S;                             // pk_mul
        bool g0 = lhs.x > rhs.x;   // strict > = first-occurrence argmax
        bool g1 = lhs.y > rhs.y;
        bI.x  = g0 ? inter.x : bI.x;
        bS.x  = g0 ? S.x     : bS.x;
        bidx0 = g0 ? j       : bidx0;
        bI.y  = g1 ? inter.y : bI.y;
        bS.y  = g1 ? S.y     : bS.y;
        bidx1 = g1 ? j       : bidx1;
    }

    // ---- epilogue: one exact divide per anchor, classify, gather, store ----
    const float IOU_LOW = 0.3f, IOU_HIGH = 0.6f, NEUTRAL = -100000000.0f;
    float* mout = out + (size_t)n * 4;

    {
        float uni = bS.x - bI.x;   // fl(fl(a1+a2) - inter): same assoc as ref
        float q = bI.x / uni;      // bit-identical to ref match_quality
        float o0, o1, o2, o3, o4;
        if (q <= IOU_LOW) {
            o0 = o1 = o2 = o3 = o4 = -1.0f;
        } else if (q < IOU_HIGH) {
            o0 = o1 = o2 = o3 = o4 = NEUTRAL;
        } else {
            float4 gbx = sbox[bidx0];
            o0 = gbx.x; o1 = gbx.y; o2 = gbx.z; o3 = gbx.w; o4 = scls[bidx0];
        }
        if (v0) {
            float* mo = mout + (size_t)i0 * 5;
            mo[0] = o0; mo[1] = o1; mo[2] = o2; mo[3] = o3; mo[4] = o4;
        }
    }
    {
        float uni = bS.y - bI.y;
        float q = bI.y / uni;
        float o0, o1, o2, o3, o4;
        if (q <= IOU_LOW) {
            o0 = o1 = o2 = o3 = o4 = -1.0f;
        } else if (q < IOU_HIGH) {
            o0 = o1 = o2 = o3 = o4 = NEUTRAL;
        } else {
            float4 gbx = sbox[bidx1];
            o0 = gbx.x; o1 = gbx.y; o2 = gbx.z; o3 = gbx.w; o4 = scls[bidx1];
        }
        if (v1) {
            float* mo = mout + (size_t)i1 * 5;
            mo[0] = o0; mo[1] = o1; mo[2] = o2; mo[3] = o3; mo[4] = o4;
        }
    }
}

extern "C" void kernel_launch(void* const* d_in, const int* in_sizes, int n_in,
                              void* d_out, int out_size, void* d_ws, size_t ws_size,
                              hipStream_t stream) {
    const float* anchors  = (const float*)d_in[0];
    const float* deltas   = (const float*)d_in[1];
    const float* gt_boxes = (const float*)d_in[2];
    float* out = (float*)d_out;

    int n = in_sizes[0] / 4;   // 400000
    int m = in_sizes[2] / 5;   // 128

    int nblocks = (n + 511) / 512;   // 2 anchors per thread
    hipLaunchKernelGGL(rpn_match_kernel, dim3(nblocks), dim3(256), 0, stream,
                       anchors, deltas, gt_boxes, out, n, m);
}